// Round 13
// baseline (94.268 us; speedup 1.0000x reference)
//
#include <hip/hip_runtime.h>
#include <hip/hip_bf16.h>

typedef float    f32x4  __attribute__((ext_vector_type(4)));
typedef float    f32x16 __attribute__((ext_vector_type(16)));
typedef int      i32x4  __attribute__((ext_vector_type(4)));
typedef _Float16 f16x8  __attribute__((ext_vector_type(8)));

#define LL 256   // h*w
#define NF 32    // hidden dim
#define NCH 64   // channels

// HW pack: two f32 -> u32 of two fp16 (v_cvt_pkrtz_f16_f32)
__device__ __forceinline__ unsigned pkrtz(float lo, float hi) {
    return __builtin_bit_cast(unsigned, __builtin_amdgcn_cvt_pkrtz(lo, hi));
}

__device__ __forceinline__ f16x8 words_to_frag(unsigned w0, unsigned w1, unsigned w2, unsigned w3) {
    i32x4 w;
    w.x = (int)w0; w.y = (int)w1; w.z = (int)w2; w.w = (int)w3;
    return __builtin_bit_cast(f16x8, w);
}

// cvt f32x16 acc -> two f16x8 frags with relu after rtz (commutes)
__device__ __forceinline__ void cvt_relu(const f32x16& a, f16x8& f0, f16x8& f1) {
    const f16x8 z8 = {};
    f0 = __builtin_elementwise_max(
        words_to_frag(pkrtz(a[0],  a[1]),  pkrtz(a[2],  a[3]),
                      pkrtz(a[4],  a[5]),  pkrtz(a[6],  a[7])), z8);
    f1 = __builtin_elementwise_max(
        words_to_frag(pkrtz(a[8],  a[9]),  pkrtz(a[10], a[11]),
                      pkrtz(a[12], a[13]), pkrtz(a[14], a[15])), z8);
}

// Transposed A' layout: Ap2[b][qtile][kh*2+hi][col][e]  (tile = 1024 halves = 2 KB)
__device__ __forceinline__ int a_perm(int l, int k) {
    return ((l >> 5) << 10) + ((((k >> 4) << 1) | ((k >> 3) & 1)) << 8) + ((l & 31) << 3) + (k & 7);
}

// ---------------- phase 0: A' (fp16, transposed); B (fp16); tables; zero arrive-counter ----------
__global__ __launch_bounds__(256) void rn_pre(
    const float* __restrict__ x, const float* __restrict__ W0,
    const float* __restrict__ b0, const float* __restrict__ W1, const float* __restrict__ b1,
    const float* __restrict__ W2, const float* __restrict__ b2,
    _Float16* __restrict__ Ap, _Float16* __restrict__ Bp,
    _Float16* __restrict__ fragTab, float* __restrict__ biasTab,
    unsigned* __restrict__ counter)
{
    int tid = threadIdx.x;
    if (blockIdx.x == 0 && tid == 0) {
        __hip_atomic_store(counter, 0u, __ATOMIC_RELAXED, __HIP_MEMORY_SCOPE_AGENT);
    }
    if (blockIdx.x == 0 && tid < 64) {
        const int hi2 = tid >> 5, colv = tid & 31;
        #pragma unroll
        for (int kh = 0; kh < 2; ++kh) {
            f16x8 f1, f2;
            #pragma unroll
            for (int e = 0; e < 8; ++e) {
                int k  = kh * 16 + 8 * hi2 + e;
                int bk = (k >> 2) & 3;
                int fk = (bk == 1 || bk == 2) ? (k ^ 12) : k;   // phi
                f1[e] = (_Float16)W1[k  * NF + colv];
                f2[e] = (_Float16)W2[fk * NF + colv];
            }
            *(f16x8*)(fragTab + ((0 + kh) * 64 + tid) * 8) = f1;
            *(f16x8*)(fragTab + ((2 + kh) * 64 + tid) * 8) = f2;
        }
        int table = tid >> 5;
        int hh    = (tid >> 4) & 1;
        int r     = tid & 15;
        int row   = (r & 3) + 8 * (r >> 2) + 4 * hh;
        biasTab[table * 32 + hh * 16 + r] = table ? b2[row] : b1[row];
    }

    int gid = blockIdx.x * 256 + tid;   // 32*256*32 = 262144 threads
    int k  = gid & 31;
    int bl = gid >> 5;          // b*256 + l
    int b  = bl >> 8;
    int l  = bl & 255;
    const float* xrow = x + b * NCH * LL + l;   // x[b][ch][l]
    float accA = 0.f, accB = 0.f;
    #pragma unroll 8
    for (int ch = 0; ch < NCH; ++ch) {
        float xv = xrow[ch * LL];
        accA += xv * W0[ch * NF + k];
        accB += xv * W0[(NCH + ch) * NF + k];
    }
    Ap[b * 8192 + a_perm(l, k)] = (_Float16)(accA + b0[k]);
    Bp[gid] = (_Float16)accB;
}

// ---------------- phase 1+2 fused: pair loop (r12 body) + last-block MLP head ----------------
// grid: 1024 blocks (XCD-swizzled). Last-block pattern is deadlock-free (no spin barrier):
// each block fences + arrives; the final arriver reads partials with agent-scope atomic loads
// (coherent across XCD L2s) and computes the head inline, replacing the rn_post launch.
__global__ __launch_bounds__(256) void rn_main(
    const _Float16* __restrict__ Ap, const _Float16* __restrict__ Bp,
    const _Float16* __restrict__ fragTab, const float* __restrict__ biasTab,
    float* __restrict__ partials, unsigned* __restrict__ counter,
    const float* __restrict__ Wp, const float* __restrict__ bp,
    const float* __restrict__ Wo, const float* __restrict__ bo,
    float* __restrict__ out)
{
    const int tid  = threadIdx.x;
    const int lane = tid & 63;
    const int w    = tid >> 6;
    const int col  = lane & 31;
    const int hi   = lane >> 5;
    const int bid  = (blockIdx.x & 7) * 128 + (blockIdx.x >> 3);
    const int batch  = bid >> 5;
    const int rem    = bid & 31;
    const int pgroup = rem >> 1;    // 0..15
    const int qchunk = rem & 1;     // 0..1
    const int pbase  = pgroup * 16 + w * 4;
    const int qtile0 = qchunk * 4;  // first of 4 q-tiles

    // ---- setup from precomputed tables ----
    f16x8 a1[2], a2[2];
    a1[0] = *(const f16x8*)(fragTab + (0 * 64 + lane) * 8);
    a1[1] = *(const f16x8*)(fragTab + (1 * 64 + lane) * 8);
    a2[0] = *(const f16x8*)(fragTab + (2 * 64 + lane) * 8);
    a2[1] = *(const f16x8*)(fragTab + (3 * 64 + lane) * 8);

    f32x16 bias1, bias2, sacc0, sacc1;
    {
        const f32x4* bt1 = (const f32x4*)(biasTab + hi * 16);
        const f32x4* bt2 = (const f32x4*)(biasTab + 32 + hi * 16);
        #pragma unroll
        for (int j = 0; j < 4; ++j) {
            f32x4 v1 = bt1[j], v2 = bt2[j];
            #pragma unroll
            for (int e = 0; e < 4; ++e) {
                bias1[j * 4 + e] = v1[e];
                bias2[j * 4 + e] = v2[e];
                sacc0[j * 4 + e] = 0.f;
                sacc1[j * 4 + e] = 0.f;
            }
        }
    }

    // ---- B rows for the wave's 4 p's ----
    f16x8 bq0[4], bq1[4];
    #pragma unroll
    for (int i = 0; i < 4; ++i) {
        const _Float16* Brow = Bp + (batch * LL + pbase + i) * NF + 8 * hi;
        bq0[i] = *(const f16x8*)(Brow);
        bq1[i] = *(const f16x8*)(Brow + 16);
    }

    // ---- A' tiles: transposed layout, fully coalesced ----
    const _Float16* Atile = Ap + batch * 8192 + qtile0 * 1024;
    const int off0 = hi * 256 + col * 8;          // kh = 0
    const int off1 = 512 + hi * 256 + col * 8;    // kh = 1

    const f16x8 z8 = {};

    f16x8 ca0 = *(const f16x8*)(Atile + off0);
    f16x8 ca1 = *(const f16x8*)(Atile + off1);

    #pragma unroll
    for (int t = 0; t < 4; ++t) {
        f16x8 na0, na1;
        if (t < 3) {
            na0 = *(const f16x8*)(Atile + (t + 1) * 1024 + off0);
            na1 = *(const f16x8*)(Atile + (t + 1) * 1024 + off1);
        }

        #pragma unroll
        for (int ig = 0; ig < 2; ++ig) {
            const int i0 = ig * 2, i1 = ig * 2 + 1;

            f16x8 h0a = __builtin_elementwise_max(ca0 + bq0[i0], z8);
            f16x8 h1a = __builtin_elementwise_max(ca1 + bq1[i0], z8);
            f16x8 h0b = __builtin_elementwise_max(ca0 + bq0[i1], z8);
            f16x8 h1b = __builtin_elementwise_max(ca1 + bq1[i1], z8);

            f32x16 acc1a = __builtin_amdgcn_mfma_f32_32x32x16_f16(a1[0], h0a, bias1, 0, 0, 0);
            f32x16 acc1b = __builtin_amdgcn_mfma_f32_32x32x16_f16(a1[0], h0b, bias1, 0, 0, 0);
            acc1a = __builtin_amdgcn_mfma_f32_32x32x16_f16(a1[1], h1a, acc1a, 0, 0, 0);
            acc1b = __builtin_amdgcn_mfma_f32_32x32x16_f16(a1[1], h1b, acc1b, 0, 0, 0);

            f16x8 h2f0a, h2f1a, h2f0b, h2f1b;
            cvt_relu(acc1a, h2f0a, h2f1a);
            cvt_relu(acc1b, h2f0b, h2f1b);

            f32x16 acc2a = __builtin_amdgcn_mfma_f32_32x32x16_f16(a2[0], h2f0a, bias2, 0, 0, 0);
            f32x16 acc2b = __builtin_amdgcn_mfma_f32_32x32x16_f16(a2[0], h2f0b, bias2, 0, 0, 0);
            acc2a = __builtin_amdgcn_mfma_f32_32x32x16_f16(a2[1], h2f1a, acc2a, 0, 0, 0);
            acc2b = __builtin_amdgcn_mfma_f32_32x32x16_f16(a2[1], h2f1b, acc2b, 0, 0, 0);

            sacc0 += __builtin_elementwise_max(acc2a, (f32x16)0.0f);
            sacc1 += __builtin_elementwise_max(acc2b, (f32x16)0.0f);
        }

        ca0 = na0;
        ca1 = na1;
    }

    f32x16 sacc = sacc0 + sacc1;

    // ---- 3-stage LDS tail reduce ----
    __shared__ float P[256 * 20];
    __shared__ float Q[8][32];
    #pragma unroll
    for (int j = 0; j < 4; ++j) {
        f32x4 v;
        v.x = sacc[j * 4 + 0]; v.y = sacc[j * 4 + 1];
        v.z = sacc[j * 4 + 2]; v.w = sacc[j * 4 + 3];
        *(f32x4*)&P[tid * 20 + j * 4] = v;
    }
    __syncthreads();
    {
        const int row  = tid & 31;
        const int part = tid >> 5;
        const int wq   = part >> 1;
        const int colh = (part & 1) << 4;
        const int hir  = (row >> 2) & 1;
        const int rr   = (row & 3) | ((row >> 3) << 2);
        const int base = (wq * 64 + hir * 32 + colh) * 20 + rr;
        float s = 0.f;
        #pragma unroll
        for (int j = 0; j < 16; ++j) s += P[base + j * 20];
        Q[part][row] = s;
    }
    __syncthreads();
    if (tid < 32) {
        float s = 0.f;
        #pragma unroll
        for (int g = 0; g < 8; ++g) s += Q[g][tid];
        partials[bid * 32 + tid] = s;
    }

    // ---- last-block arrive + inline MLP head (deadlock-free, no spin) ----
    __shared__ int lastFlag;
    __threadfence();            // publish partials (L2 writeback) before arriving
    __syncthreads();
    if (tid == 0)
        lastFlag = (atomicAdd(counter, 1u) == (unsigned)(gridDim.x - 1));
    __syncthreads();
    if (!lastFlag) return;

    __shared__ float sb[32][32];
    __shared__ float fb[32][32];
    #pragma unroll
    for (int m = 0; m < 4; ++m) {
        int idx = tid + 256 * m;          // (b,n)
        int b = idx >> 5, n = idx & 31;
        float s = 0.f;
        #pragma unroll 4
        for (int c = 0; c < 32; ++c)
            s += __hip_atomic_load((float*)&partials[(b * 32 + c) * 32 + n],
                                   __ATOMIC_RELAXED, __HIP_MEMORY_SCOPE_AGENT);
        sb[b][n] = s;
    }
    __syncthreads();
    #pragma unroll
    for (int m = 0; m < 4; ++m) {
        int idx = tid + 256 * m;
        int b = idx >> 5, n = idx & 31;
        float f = bp[n];
        #pragma unroll
        for (int k = 0; k < 32; ++k) f += sb[b][k] * Wp[k * 32 + n];
        fb[b][n] = fmaxf(f, 0.f);
    }
    __syncthreads();
    #pragma unroll
    for (int m = 0; m < 4; ++m) {
        int idx = tid + 256 * m;
        int b = idx >> 5, n = idx & 31;
        float o = bo[n];
        #pragma unroll
        for (int k = 0; k < 32; ++k) o += fb[b][k] * Wo[k * 32 + n];
        out[b * 32 + n] = o;
    }
}

extern "C" void kernel_launch(void* const* d_in, const int* in_sizes, int n_in,
                              void* d_out, int out_size, void* d_ws, size_t ws_size,
                              hipStream_t stream)
{
    const float* x  = (const float*)d_in[0];
    const float* W0 = (const float*)d_in[1];
    const float* b0 = (const float*)d_in[2];
    const float* W1 = (const float*)d_in[3];
    const float* b1 = (const float*)d_in[4];
    const float* W2 = (const float*)d_in[5];
    const float* b2 = (const float*)d_in[6];
    const float* Wp = (const float*)d_in[7];
    const float* bp = (const float*)d_in[8];
    const float* Wo = (const float*)d_in[9];
    const float* bo = (const float*)d_in[10];
    float* out = (float*)d_out;

    _Float16* Ap       = (_Float16*)d_ws;                 // 262144 halves (512 KB, transposed)
    _Float16* Bp       = Ap + 32 * LL * NF;               // 262144 halves (512 KB)
    float*    partials = (float*)(Bp + 32 * LL * NF);     // 1024*32 f32 (128 KB)
    _Float16* fragTab  = (_Float16*)(partials + 2048 * 32);  // 4*64*8 halves (4 KB)
    float*    biasTab  = (float*)(fragTab + 4 * 64 * 8);     // 64 f32 (256 B)
    unsigned* counter  = (unsigned*)(biasTab + 64);          // 1 u32 arrive counter

    rn_pre <<<1024, 256, 0, stream>>>(x, W0, b0, W1, b1, W2, b2, Ap, Bp,
                                      fragTab, biasTab, counter);
    rn_main<<<1024, 256, 0, stream>>>(Ap, Bp, fragTab, biasTab, partials, counter,
                                      Wp, bp, Wo, bo, out);
}

// Round 14
// 30.795 us; speedup vs baseline: 3.0611x; 3.0611x over previous
//
#include <hip/hip_runtime.h>
#include <hip/hip_bf16.h>

typedef float    f32x4  __attribute__((ext_vector_type(4)));
typedef float    f32x16 __attribute__((ext_vector_type(16)));
typedef int      i32x4  __attribute__((ext_vector_type(4)));
typedef _Float16 f16x8  __attribute__((ext_vector_type(8)));

#define LL 256   // h*w
#define NF 32    // hidden dim
#define NCH 64   // channels

// HW pack: two f32 -> u32 of two fp16 (v_cvt_pkrtz_f16_f32)
__device__ __forceinline__ unsigned pkrtz(float lo, float hi) {
    return __builtin_bit_cast(unsigned, __builtin_amdgcn_cvt_pkrtz(lo, hi));
}

__device__ __forceinline__ f16x8 words_to_frag(unsigned w0, unsigned w1, unsigned w2, unsigned w3) {
    i32x4 w;
    w.x = (int)w0; w.y = (int)w1; w.z = (int)w2; w.w = (int)w3;
    return __builtin_bit_cast(f16x8, w);
}

// cvt f32x16 acc -> two f16x8 frags with relu after rtz (commutes)
__device__ __forceinline__ void cvt_relu(const f32x16& a, f16x8& f0, f16x8& f1) {
    const f16x8 z8 = {};
    f0 = __builtin_elementwise_max(
        words_to_frag(pkrtz(a[0],  a[1]),  pkrtz(a[2],  a[3]),
                      pkrtz(a[4],  a[5]),  pkrtz(a[6],  a[7])), z8);
    f1 = __builtin_elementwise_max(
        words_to_frag(pkrtz(a[8],  a[9]),  pkrtz(a[10], a[11]),
                      pkrtz(a[12], a[13]), pkrtz(a[14], a[15])), z8);
}

// Transposed A' layout: Ap2[b][qtile][kh*2+hi][col][e]  (tile = 1024 halves = 2 KB)
__device__ __forceinline__ int a_perm(int l, int k) {
    return ((l >> 5) << 10) + ((((k >> 4) << 1) | ((k >> 3) & 1)) << 8) + ((l & 31) << 3) + (k & 7);
}

// ---------------- phase 0: A' (fp16, transposed); B (fp16); lane tables ----------------
__global__ __launch_bounds__(256) void rn_pre(
    const float* __restrict__ x, const float* __restrict__ W0,
    const float* __restrict__ b0, const float* __restrict__ W1, const float* __restrict__ b1,
    const float* __restrict__ W2, const float* __restrict__ b2,
    _Float16* __restrict__ Ap, _Float16* __restrict__ Bp,
    _Float16* __restrict__ fragTab, float* __restrict__ biasTab)
{
    int tid = threadIdx.x;
    if (blockIdx.x == 0 && tid < 64) {
        const int hi2 = tid >> 5, colv = tid & 31;
        #pragma unroll
        for (int kh = 0; kh < 2; ++kh) {
            f16x8 f1, f2;
            #pragma unroll
            for (int e = 0; e < 8; ++e) {
                int k  = kh * 16 + 8 * hi2 + e;
                int bk = (k >> 2) & 3;
                int fk = (bk == 1 || bk == 2) ? (k ^ 12) : k;   // phi
                f1[e] = (_Float16)W1[k  * NF + colv];
                f2[e] = (_Float16)W2[fk * NF + colv];
            }
            *(f16x8*)(fragTab + ((0 + kh) * 64 + tid) * 8) = f1;
            *(f16x8*)(fragTab + ((2 + kh) * 64 + tid) * 8) = f2;
        }
        int table = tid >> 5;
        int hh    = (tid >> 4) & 1;
        int r     = tid & 15;
        int row   = (r & 3) + 8 * (r >> 2) + 4 * hh;
        biasTab[table * 32 + hh * 16 + r] = table ? b2[row] : b1[row];
    }

    int gid = blockIdx.x * 256 + tid;   // 32*256*32 = 262144 threads
    int k  = gid & 31;
    int bl = gid >> 5;          // b*256 + l
    int b  = bl >> 8;
    int l  = bl & 255;
    const float* xrow = x + b * NCH * LL + l;   // x[b][ch][l]
    float accA = 0.f, accB = 0.f;
    #pragma unroll 8
    for (int ch = 0; ch < NCH; ++ch) {
        float xv = xrow[ch * LL];
        accA += xv * W0[ch * NF + k];
        accB += xv * W0[(NCH + ch) * NF + k];
    }
    Ap[b * 8192 + a_perm(l, k)] = (_Float16)(accA + b0[k]);
    Bp[gid] = (_Float16)accB;
}

// ---------------- phase 1: fused pair loop (r12 staged body @ r9 grid) ----------------
// grid: 2048 blocks (XCD-swizzled) = 32 batches x 16 pgroups x 4 qchunks; 256 threads (4 waves).
// Wave owns 4 consecutive p's x 2 q-tiles; chains staged in pairs with separate accumulators.
__global__ __launch_bounds__(256) void rn_main(
    const _Float16* __restrict__ Ap, const _Float16* __restrict__ Bp,
    const _Float16* __restrict__ fragTab, const float* __restrict__ biasTab,
    float* __restrict__ partials)
{
    const int tid  = threadIdx.x;
    const int lane = tid & 63;
    const int w    = tid >> 6;
    const int col  = lane & 31;
    const int hi   = lane >> 5;
    // bijective XCD-contiguous swizzle (2048 % 8 == 0)
    const int bid  = (blockIdx.x & 7) * 256 + (blockIdx.x >> 3);
    const int batch  = bid >> 6;
    const int rem    = bid & 63;
    const int pgroup = rem >> 2;    // 0..15
    const int qchunk = rem & 3;     // 0..3
    const int pbase  = pgroup * 16 + w * 4;
    const int qtile0 = qchunk * 2;  // 2 q-tiles per wave

    // ---- setup from precomputed tables ----
    f16x8 a1[2], a2[2];
    a1[0] = *(const f16x8*)(fragTab + (0 * 64 + lane) * 8);
    a1[1] = *(const f16x8*)(fragTab + (1 * 64 + lane) * 8);
    a2[0] = *(const f16x8*)(fragTab + (2 * 64 + lane) * 8);
    a2[1] = *(const f16x8*)(fragTab + (3 * 64 + lane) * 8);

    f32x16 bias1, bias2, sacc0, sacc1;
    {
        const f32x4* bt1 = (const f32x4*)(biasTab + hi * 16);
        const f32x4* bt2 = (const f32x4*)(biasTab + 32 + hi * 16);
        #pragma unroll
        for (int j = 0; j < 4; ++j) {
            f32x4 v1 = bt1[j], v2 = bt2[j];
            #pragma unroll
            for (int e = 0; e < 4; ++e) {
                bias1[j * 4 + e] = v1[e];
                bias2[j * 4 + e] = v2[e];
                sacc0[j * 4 + e] = 0.f;
                sacc1[j * 4 + e] = 0.f;
            }
        }
    }

    // ---- B rows for the wave's 4 p's ----
    f16x8 bq0[4], bq1[4];
    #pragma unroll
    for (int i = 0; i < 4; ++i) {
        const _Float16* Brow = Bp + (batch * LL + pbase + i) * NF + 8 * hi;
        bq0[i] = *(const f16x8*)(Brow);
        bq1[i] = *(const f16x8*)(Brow + 16);
    }

    // ---- A' tiles: transposed layout, fully coalesced ----
    const _Float16* Atile = Ap + batch * 8192 + qtile0 * 1024;
    const int off0 = hi * 256 + col * 8;          // kh = 0
    const int off1 = 512 + hi * 256 + col * 8;    // kh = 1

    const f16x8 z8 = {};

    f16x8 ca0 = *(const f16x8*)(Atile + off0);
    f16x8 ca1 = *(const f16x8*)(Atile + off1);

    #pragma unroll
    for (int t = 0; t < 2; ++t) {
        f16x8 na0, na1;
        if (t < 1) {
            na0 = *(const f16x8*)(Atile + 1024 + off0);
            na1 = *(const f16x8*)(Atile + 1024 + off1);
        }

        #pragma unroll
        for (int ig = 0; ig < 2; ++ig) {
            const int i0 = ig * 2, i1 = ig * 2 + 1;

            // stage 1: both chains' h1 fragments
            f16x8 h0a = __builtin_elementwise_max(ca0 + bq0[i0], z8);
            f16x8 h1a = __builtin_elementwise_max(ca1 + bq1[i0], z8);
            f16x8 h0b = __builtin_elementwise_max(ca0 + bq0[i1], z8);
            f16x8 h1b = __builtin_elementwise_max(ca1 + bq1[i1], z8);

            // stage 2: 4x layer-1 MFMA
            f32x16 acc1a = __builtin_amdgcn_mfma_f32_32x32x16_f16(a1[0], h0a, bias1, 0, 0, 0);
            f32x16 acc1b = __builtin_amdgcn_mfma_f32_32x32x16_f16(a1[0], h0b, bias1, 0, 0, 0);
            acc1a = __builtin_amdgcn_mfma_f32_32x32x16_f16(a1[1], h1a, acc1a, 0, 0, 0);
            acc1b = __builtin_amdgcn_mfma_f32_32x32x16_f16(a1[1], h1b, acc1b, 0, 0, 0);

            // stage 3: both cvt epilogues
            f16x8 h2f0a, h2f1a, h2f0b, h2f1b;
            cvt_relu(acc1a, h2f0a, h2f1a);
            cvt_relu(acc1b, h2f0b, h2f1b);

            // stage 4: 4x layer-2 MFMA
            f32x16 acc2a = __builtin_amdgcn_mfma_f32_32x32x16_f16(a2[0], h2f0a, bias2, 0, 0, 0);
            f32x16 acc2b = __builtin_amdgcn_mfma_f32_32x32x16_f16(a2[0], h2f0b, bias2, 0, 0, 0);
            acc2a = __builtin_amdgcn_mfma_f32_32x32x16_f16(a2[1], h2f1a, acc2a, 0, 0, 0);
            acc2b = __builtin_amdgcn_mfma_f32_32x32x16_f16(a2[1], h2f1b, acc2b, 0, 0, 0);

            // stage 5: independent accumulators
            sacc0 += __builtin_elementwise_max(acc2a, (f32x16)0.0f);
            sacc1 += __builtin_elementwise_max(acc2b, (f32x16)0.0f);
        }

        ca0 = na0;
        ca1 = na1;
    }

    f32x16 sacc = sacc0 + sacc1;

    // ---- 3-stage LDS tail reduce ----
    __shared__ float P[256 * 20];
    __shared__ float Q[8][32];
    #pragma unroll
    for (int j = 0; j < 4; ++j) {
        f32x4 v;
        v.x = sacc[j * 4 + 0]; v.y = sacc[j * 4 + 1];
        v.z = sacc[j * 4 + 2]; v.w = sacc[j * 4 + 3];
        *(f32x4*)&P[tid * 20 + j * 4] = v;
    }
    __syncthreads();
    {
        const int row  = tid & 31;
        const int part = tid >> 5;
        const int wq   = part >> 1;
        const int colh = (part & 1) << 4;
        const int hir  = (row >> 2) & 1;
        const int rr   = (row & 3) | ((row >> 3) << 2);
        const int base = (wq * 64 + hir * 32 + colh) * 20 + rr;
        float s = 0.f;
        #pragma unroll
        for (int j = 0; j < 16; ++j) s += P[base + j * 20];
        Q[part][row] = s;
    }
    __syncthreads();
    if (tid < 32) {
        float s = 0.f;
        #pragma unroll
        for (int g = 0; g < 8; ++g) s += Q[g][tid];
        partials[bid * 32 + tid] = s;   // bid = batch*64 + rem : contiguous per batch
    }
}

// ---------------- phase 2: per-batch reduce + MLP head (32 blocks) ----------------
__global__ __launch_bounds__(256) void rn_post(
    const float* __restrict__ partials,
    const float* __restrict__ Wp, const float* __restrict__ bp,
    const float* __restrict__ Wo, const float* __restrict__ bo,
    float* __restrict__ out)
{
    const int b   = blockIdx.x;       // 32 blocks, one per batch
    const int tid = threadIdx.x;      // 256 threads
    const int grp = tid >> 5, n = tid & 31;
    __shared__ float red[8][32];
    float s = 0.f;
    #pragma unroll
    for (int j = 0; j < 8; ++j)
        s += partials[(b * 64 + grp * 8 + j) * 32 + n];
    red[grp][n] = s;
    __syncthreads();
    if (tid < 32) {
        float sv = 0.f;
        #pragma unroll
        for (int g = 0; g < 8; ++g) sv += red[g][tid];
        float f = bp[tid];
        #pragma unroll
        for (int k = 0; k < 32; ++k)
            f += __shfl(sv, k, 32) * Wp[k * 32 + tid];
        f = fmaxf(f, 0.f);
        float o = bo[tid];
        #pragma unroll
        for (int k = 0; k < 32; ++k)
            o += __shfl(f, k, 32) * Wo[k * 32 + tid];
        out[b * 32 + tid] = o;
    }
}

extern "C" void kernel_launch(void* const* d_in, const int* in_sizes, int n_in,
                              void* d_out, int out_size, void* d_ws, size_t ws_size,
                              hipStream_t stream)
{
    const float* x  = (const float*)d_in[0];
    const float* W0 = (const float*)d_in[1];
    const float* b0 = (const float*)d_in[2];
    const float* W1 = (const float*)d_in[3];
    const float* b1 = (const float*)d_in[4];
    const float* W2 = (const float*)d_in[5];
    const float* b2 = (const float*)d_in[6];
    const float* Wp = (const float*)d_in[7];
    const float* bp = (const float*)d_in[8];
    const float* Wo = (const float*)d_in[9];
    const float* bo = (const float*)d_in[10];
    float* out = (float*)d_out;

    _Float16* Ap       = (_Float16*)d_ws;                 // 262144 halves (512 KB, transposed)
    _Float16* Bp       = Ap + 32 * LL * NF;               // 262144 halves (512 KB)
    float*    partials = (float*)(Bp + 32 * LL * NF);     // 2048*32 f32 (256 KB)
    _Float16* fragTab  = (_Float16*)(partials + 2048 * 32);  // 4*64*8 halves (4 KB)
    float*    biasTab  = (float*)(fragTab + 4 * 64 * 8);     // 64 f32 (256 B)

    rn_pre <<<1024, 256, 0, stream>>>(x, W0, b0, W1, b1, W2, b2, Ap, Bp, fragTab, biasTab);
    rn_main<<<2048, 256, 0, stream>>>(Ap, Bp, fragTab, biasTab, partials);
    rn_post<<<32, 256, 0, stream>>>(partials, Wp, bp, Wo, bo, out);
}

// Round 15
// 23.733 us; speedup vs baseline: 3.9719x; 1.2975x over previous
//
#include <hip/hip_runtime.h>
#include <hip/hip_bf16.h>

typedef float    f32x4  __attribute__((ext_vector_type(4)));
typedef float    f32x16 __attribute__((ext_vector_type(16)));
typedef int      i32x4  __attribute__((ext_vector_type(4)));
typedef _Float16 f16x8  __attribute__((ext_vector_type(8)));

#define LL 256   // h*w
#define NF 32    // hidden dim
#define NCH 64   // channels

// HW pack: two f32 -> u32 of two fp16 (v_cvt_pkrtz_f16_f32)
__device__ __forceinline__ unsigned pkrtz(float lo, float hi) {
    return __builtin_bit_cast(unsigned, __builtin_amdgcn_cvt_pkrtz(lo, hi));
}

__device__ __forceinline__ f16x8 words_to_frag(unsigned w0, unsigned w1, unsigned w2, unsigned w3) {
    i32x4 w;
    w.x = (int)w0; w.y = (int)w1; w.z = (int)w2; w.w = (int)w3;
    return __builtin_bit_cast(f16x8, w);
}

// cvt f32x16 acc -> two f16x8 frags with relu after rtz (commutes)
__device__ __forceinline__ void cvt_relu(const f32x16& a, f16x8& f0, f16x8& f1) {
    const f16x8 z8 = {};
    f0 = __builtin_elementwise_max(
        words_to_frag(pkrtz(a[0],  a[1]),  pkrtz(a[2],  a[3]),
                      pkrtz(a[4],  a[5]),  pkrtz(a[6],  a[7])), z8);
    f1 = __builtin_elementwise_max(
        words_to_frag(pkrtz(a[8],  a[9]),  pkrtz(a[10], a[11]),
                      pkrtz(a[12], a[13]), pkrtz(a[14], a[15])), z8);
}

// phi: C/D-row -> B-slot feature relabel (same permutation for W1 and W2 folds)
__device__ __forceinline__ int phik(int k) {
    int bk = (k >> 2) & 3;
    return (bk == 1 || bk == 2) ? (k ^ 12) : k;
}

// ---------------- single fused kernel: x -> A'/B (MFMA, in-block) -> pair loop -> partials -------
// grid: 512 blocks (XCD-swizzled) = 32 batches x 16 pblocks; 256 threads (4 waves); 2 blocks/CU.
// Each block: stage x^T (f16) to LDS; compute A' (8 qtiles, split over waves, b0 via C-init) and
// the 16-p B-tile with MFMAs; then wave = 4 p's x 8 qtiles of the relational pair loop.
// A' C/D-regs feed layer-1 directly because phi is folded into the W1 table (same trick as W2/r3).
__global__ __launch_bounds__(256, 2) void rn_all(
    const float* __restrict__ x, const float* __restrict__ W0, const float* __restrict__ b0,
    const float* __restrict__ W1, const float* __restrict__ b1,
    const float* __restrict__ W2, const float* __restrict__ b2,
    float* __restrict__ partials)
{
    __shared__ __align__(16) unsigned char uXT[256 * 144]; // 36.9KB x^T rows; aliased by tail P/Q
    __shared__ unsigned AldsU[8 * 64 * 9];                 // 18.4KB A' frags, stride 9 dw (odd: conflict-free)
    __shared__ unsigned Blds[16 * 2 * 8];                  // 1KB B-tile words

    const int tid  = threadIdx.x;
    const int lane = tid & 63;
    const int w    = tid >> 6;
    const int col  = lane & 31;
    const int hi   = lane >> 5;
    const int bid  = (blockIdx.x & 7) * 64 + (blockIdx.x >> 3);   // bijective, 512 % 8 == 0
    const int batch  = bid >> 4;
    const int pblock = bid & 15;

    // ---- stage x^T[l][ch] as f16, row stride 144B (coalesced reads, b128 row writes) ----
    const float* xb = x + batch * NCH * LL;
    #pragma unroll
    for (int c8 = 0; c8 < 8; ++c8) {
        float v0 = xb[(c8*8+0)*LL + tid], v1 = xb[(c8*8+1)*LL + tid];
        float v2 = xb[(c8*8+2)*LL + tid], v3 = xb[(c8*8+3)*LL + tid];
        float v4 = xb[(c8*8+4)*LL + tid], v5 = xb[(c8*8+5)*LL + tid];
        float v6 = xb[(c8*8+6)*LL + tid], v7 = xb[(c8*8+7)*LL + tid];
        i32x4 pk;
        pk.x = (int)pkrtz(v0, v1); pk.y = (int)pkrtz(v2, v3);
        pk.z = (int)pkrtz(v4, v5); pk.w = (int)pkrtz(v6, v7);
        *(i32x4*)(uXT + tid * 144 + c8 * 16) = pk;
    }

    // ---- one-time per-lane tables (coalesced 128B gathers, L2-hot) ----
    f16x8 a1[2], a2[2], wa[4];
    #pragma unroll
    for (int kh = 0; kh < 2; ++kh) {
        #pragma unroll
        for (int e = 0; e < 8; ++e) {
            int k  = kh * 16 + 8 * hi + e;
            int fk = phik(k);                     // phi fold on BOTH W1 (A' in C/D order) and W2
            a1[kh][e] = (_Float16)W1[fk * NF + col];
            a2[kh][e] = (_Float16)W2[fk * NF + col];
        }
    }
    #pragma unroll
    for (int kk = 0; kk < 4; ++kk)
        #pragma unroll
        for (int e = 0; e < 8; ++e)
            wa[kk][e] = (_Float16)W0[(kk * 16 + 8 * hi + e) * NF + col];

    f32x16 bias1, bias2, breg, sacc0, sacc1;
    #pragma unroll
    for (int r = 0; r < 16; ++r) {
        int row = (r & 3) + 8 * (r >> 2) + 4 * hi;
        bias1[r] = b1[row]; bias2[r] = b2[row]; breg[r] = b0[row];
        sacc0[r] = 0.f; sacc1[r] = 0.f;
    }

    __syncthreads();   // x^T ready

    // ---- pre-GEMM A': wave w owns qtiles 2w, 2w+1; D = W0^T x^T + b0 (C-init) ----
    #pragma unroll
    for (int j = 0; j < 2; ++j) {
        int qt = 2 * w + j;
        f32x16 d = breg;
        #pragma unroll
        for (int kk = 0; kk < 4; ++kk) {
            f16x8 xf = *(const f16x8*)(uXT + (qt * 32 + col) * 144 + kk * 32 + hi * 16);
            d = __builtin_amdgcn_mfma_f32_32x32x16_f16(wa[kk], xf, d, 0, 0, 0);
        }
        unsigned* ab = AldsU + (qt * 64 + lane) * 9;
        #pragma unroll
        for (int jj = 0; jj < 8; ++jj) ab[jj] = pkrtz(d[2*jj], d[2*jj+1]);
    }
    // ---- wave 0: B-tile for the block's 16 p's ----
    if (w == 0) {
        f16x8 wb[4];
        #pragma unroll
        for (int kk = 0; kk < 4; ++kk)
            #pragma unroll
            for (int e = 0; e < 8; ++e)
                wb[kk][e] = (_Float16)W0[(NCH + kk * 16 + 8 * hi + e) * NF + col];
        f32x16 d = (f32x16)0.0f;
        #pragma unroll
        for (int kk = 0; kk < 4; ++kk) {
            f16x8 xf = *(const f16x8*)(uXT + (pblock * 16 + (col & 15)) * 144 + kk * 32 + hi * 16);
            d = __builtin_amdgcn_mfma_f32_32x32x16_f16(wb[kk], xf, d, 0, 0, 0);
        }
        if (col < 16) {
            unsigned* bb = Blds + col * 16 + hi * 8;
            i32x4 lo, h4;
            lo.x = (int)pkrtz(d[0],  d[1]);  lo.y = (int)pkrtz(d[2],  d[3]);
            lo.z = (int)pkrtz(d[4],  d[5]);  lo.w = (int)pkrtz(d[6],  d[7]);
            h4.x = (int)pkrtz(d[8],  d[9]);  h4.y = (int)pkrtz(d[10], d[11]);
            h4.z = (int)pkrtz(d[12], d[13]); h4.w = (int)pkrtz(d[14], d[15]);
            *(i32x4*)bb       = lo;
            *(i32x4*)(bb + 4) = h4;
        }
    }
    __syncthreads();   // A' + B ready

    // ---- bq frags for the wave's 4 p's (broadcast reads) ----
    f16x8 bq0[4], bq1[4];
    #pragma unroll
    for (int i = 0; i < 4; ++i) {
        const unsigned* bb = Blds + (w * 4 + i) * 16 + hi * 8;
        bq0[i] = __builtin_bit_cast(f16x8, *(const i32x4*)bb);
        bq1[i] = __builtin_bit_cast(f16x8, *(const i32x4*)(bb + 4));
    }

    const f16x8 z8 = {};

    // ---- main pair loop: 8 qtiles x 4 p's (staged pairs, r12-verified body) ----
    #pragma unroll 2
    for (int qt = 0; qt < 8; ++qt) {
        const unsigned* ab = AldsU + (qt * 64 + lane) * 9;
        f16x8 ca0 = words_to_frag(ab[0], ab[1], ab[2], ab[3]);
        f16x8 ca1 = words_to_frag(ab[4], ab[5], ab[6], ab[7]);

        #pragma unroll
        for (int ig = 0; ig < 2; ++ig) {
            const int i0 = ig * 2, i1 = ig * 2 + 1;

            f16x8 h0a = __builtin_elementwise_max(ca0 + bq0[i0], z8);
            f16x8 h1a = __builtin_elementwise_max(ca1 + bq1[i0], z8);
            f16x8 h0b = __builtin_elementwise_max(ca0 + bq0[i1], z8);
            f16x8 h1b = __builtin_elementwise_max(ca1 + bq1[i1], z8);

            f32x16 acc1a = __builtin_amdgcn_mfma_f32_32x32x16_f16(a1[0], h0a, bias1, 0, 0, 0);
            f32x16 acc1b = __builtin_amdgcn_mfma_f32_32x32x16_f16(a1[0], h0b, bias1, 0, 0, 0);
            acc1a = __builtin_amdgcn_mfma_f32_32x32x16_f16(a1[1], h1a, acc1a, 0, 0, 0);
            acc1b = __builtin_amdgcn_mfma_f32_32x32x16_f16(a1[1], h1b, acc1b, 0, 0, 0);

            f16x8 h2f0a, h2f1a, h2f0b, h2f1b;
            cvt_relu(acc1a, h2f0a, h2f1a);
            cvt_relu(acc1b, h2f0b, h2f1b);

            f32x16 acc2a = __builtin_amdgcn_mfma_f32_32x32x16_f16(a2[0], h2f0a, bias2, 0, 0, 0);
            f32x16 acc2b = __builtin_amdgcn_mfma_f32_32x32x16_f16(a2[0], h2f0b, bias2, 0, 0, 0);
            acc2a = __builtin_amdgcn_mfma_f32_32x32x16_f16(a2[1], h2f1a, acc2a, 0, 0, 0);
            acc2b = __builtin_amdgcn_mfma_f32_32x32x16_f16(a2[1], h2f1b, acc2b, 0, 0, 0);

            sacc0 += __builtin_elementwise_max(acc2a, (f32x16)0.0f);
            sacc1 += __builtin_elementwise_max(acc2b, (f32x16)0.0f);
        }
    }

    f32x16 sacc = sacc0 + sacc1;

    // ---- 3-stage LDS tail reduce (P/Q alias the dead x^T region) ----
    float* P = reinterpret_cast<float*>(uXT);            // 256*20 f32 = 20480B
    float* Q = reinterpret_cast<float*>(uXT + 20480);    // 8*32 f32
    #pragma unroll
    for (int j = 0; j < 4; ++j) {
        f32x4 v;
        v.x = sacc[j*4+0]; v.y = sacc[j*4+1]; v.z = sacc[j*4+2]; v.w = sacc[j*4+3];
        *(f32x4*)&P[tid * 20 + j * 4] = v;
    }
    __syncthreads();
    {
        const int row  = tid & 31;
        const int part = tid >> 5;
        const int wq   = part >> 1;
        const int colh = (part & 1) << 4;
        const int hir  = (row >> 2) & 1;
        const int rr   = (row & 3) | ((row >> 3) << 2);
        const int base = (wq * 64 + hir * 32 + colh) * 20 + rr;
        float s = 0.f;
        #pragma unroll
        for (int j = 0; j < 16; ++j) s += P[base + j * 20];
        Q[part * 32 + row] = s;
    }
    __syncthreads();
    if (tid < 32) {
        float s = 0.f;
        #pragma unroll
        for (int g = 0; g < 8; ++g) s += Q[g * 32 + tid];
        partials[bid * 32 + tid] = s;   // bid = batch*16 + pblock : contiguous per batch
    }
}

// ---------------- phase 2: per-batch reduce + MLP head (32 blocks) ----------------
__global__ __launch_bounds__(256) void rn_post(
    const float* __restrict__ partials,
    const float* __restrict__ Wp, const float* __restrict__ bp,
    const float* __restrict__ Wo, const float* __restrict__ bo,
    float* __restrict__ out)
{
    const int b   = blockIdx.x;       // 32 blocks, one per batch
    const int tid = threadIdx.x;      // 256 threads
    const int grp = tid >> 5, n = tid & 31;
    __shared__ float red[8][32];
    float s = 0.f;
    #pragma unroll
    for (int j = 0; j < 2; ++j)
        s += partials[(b * 16 + grp * 2 + j) * 32 + n];
    red[grp][n] = s;
    __syncthreads();
    if (tid < 32) {
        float sv = 0.f;
        #pragma unroll
        for (int g = 0; g < 8; ++g) sv += red[g][tid];
        float f = bp[tid];
        #pragma unroll
        for (int k = 0; k < 32; ++k)
            f += __shfl(sv, k, 32) * Wp[k * 32 + tid];
        f = fmaxf(f, 0.f);
        float o = bo[tid];
        #pragma unroll
        for (int k = 0; k < 32; ++k)
            o += __shfl(f, k, 32) * Wo[k * 32 + tid];
        out[b * 32 + tid] = o;
    }
}

extern "C" void kernel_launch(void* const* d_in, const int* in_sizes, int n_in,
                              void* d_out, int out_size, void* d_ws, size_t ws_size,
                              hipStream_t stream)
{
    const float* x  = (const float*)d_in[0];
    const float* W0 = (const float*)d_in[1];
    const float* b0 = (const float*)d_in[2];
    const float* W1 = (const float*)d_in[3];
    const float* b1 = (const float*)d_in[4];
    const float* W2 = (const float*)d_in[5];
    const float* b2 = (const float*)d_in[6];
    const float* Wp = (const float*)d_in[7];
    const float* bp = (const float*)d_in[8];
    const float* Wo = (const float*)d_in[9];
    const float* bo = (const float*)d_in[10];
    float* out = (float*)d_out;

    float* partials = (float*)d_ws;    // 512*32 f32 (64 KB)

    rn_all <<<512, 256, 0, stream>>>(x, W0, b0, W1, b1, W2, b2, partials);
    rn_post<<<32, 256, 0, stream>>>(partials, Wp, bp, Wo, bo, out);
}